// Round 7
// baseline (85.986 us; speedup 1.0000x reference)
//
#include <hip/hip_runtime.h>
#include <stdint.h>

#define NCLS 80
#define BGI 80
#define BB 16
#define NGT 32
#define MM 33600
#define EPSF 1e-9f
#define CAP 512

// IoU exactly mirroring reference pairwise_iou op order; no FMA contraction.
__device__ __forceinline__ float iou_f(const float4 b1, const float4 b2) {
#pragma clang fp contract(off)
  float ltx = fmaxf(b1.x, b2.x);
  float lty = fmaxf(b1.y, b2.y);
  float rbx = fminf(b1.z, b2.z);
  float rby = fminf(b1.w, b2.w);
  float iw = fmaxf(rbx - ltx, 0.0f);
  float ih = fmaxf(rby - lty, 0.0f);
  float inter = iw * ih;
  float a1 = (b1.z - b1.x) * (b1.w - b1.y);
  float a2 = (b2.z - b2.x) * (b2.w - b2.y);
  return inter / (a1 + a2 - inter + EPSF);
}

// P0: precompute anchor centers (same op order as reference anchor_points)
// and zero the per-(b,anchor) candidate counters. 2100*256 == 537600 exact.
__global__ __launch_bounds__(256) void k_prep(
    const float4* __restrict__ anchors, float2* __restrict__ centers,
    unsigned int* __restrict__ cnt) {
#pragma clang fp contract(off)
  const int i = blockIdx.x * 256 + threadIdx.x;
  if (i < MM) {
    const float4 ab = anchors[i];
    centers[i] = make_float2((ab.x + ab.z) * 0.5f, (ab.y + ab.w) * 0.5f);
  }
  cnt[i] = 0u;
}

// 9th-smallest of 16 values (rank compute, fully unrolled, branch-free-ish).
// Computed redundantly by every thread from LDS broadcasts — no barrier.
__device__ __forceinline__ float ninth_of_16(const float* __restrict__ w) {
  float T = 0.0f;
#pragma unroll
  for (int c = 0; c < 16; ++c) {
    const float v = w[c];
    int r = 0;
#pragma unroll
    for (int q = 0; q < 16; ++q) {
      const float o = w[q];
      r += (o < v) || (o == v && q < c);
    }
    if (r == 8) T = v;  // ranks unique -> exactly one c matches
  }
  return T;
}

// K1: one 1024-thread block per (b,g). Bound-then-rank top-9, all three
// levels fused per phase -> exactly 3 block barriers.
//  phase A: per-thread min per level -> per-wave minima (3x16 in LDS).
//  phase B: T_lev = 9th smallest of the 16 wave minima (valid bound: the 9
//           smallest wave-minima are 9 distinct elements <= T, so the true
//           9th-smallest K9 <= T). Re-scan, push keys (distbits<<32|idx)
//           with dist <= T into per-level LDS buffers.
//  phase C: rank-select (rank = #smaller keys; keys unique via idx low bits;
//           equal-dist ties -> smaller index, matching lax.top_k).
__global__ __launch_bounds__(1024) void k_topk(
    const float4* __restrict__ anchors, const float2* __restrict__ centers,
    const float4* __restrict__ gtb, const float* __restrict__ maskgt,
    unsigned int* __restrict__ cnt, unsigned int* __restrict__ gidx) {
#pragma clang fp contract(off)
  const int pair = blockIdx.x;            // b*32+g
  if (maskgt[pair] == 0.0f) return;       // masked gt contributes nothing
  const int b = pair >> 5;
  const int g = pair & 31;
  const int tid = threadIdx.x;
  const int lane = tid & 63;
  const int wid = tid >> 6;
  const float4 gb = gtb[pair];
  const float gcx = (gb.x + gb.z) * 0.5f;
  const float gcy = (gb.y + gb.w) * 0.5f;

  __shared__ unsigned long long buf[3][CAP];
  __shared__ unsigned long long winners[27];
  __shared__ float s_wmin[3][16];
  __shared__ unsigned int s_cnt[3];

  if (tid == 0) { s_cnt[0] = 0u; s_cnt[1] = 0u; s_cnt[2] = 0u; }
  // first use of s_cnt is after barrier A -> visible.

  // ---- phase A: fused per-level scans (max MLP, no intervening barriers)
  float mn0 = 3.4e38f, mn1 = 3.4e38f, mn2 = 3.4e38f;
  for (int j = tid; j < 25600; j += 1024) {
    const float2 ac = centers[j];
    const float dx = gcx - ac.x;
    const float dy = gcy - ac.y;
    mn0 = fminf(mn0, sqrtf(dx * dx + dy * dy));
  }
  for (int j = tid; j < 6400; j += 1024) {
    const float2 ac = centers[25600 + j];
    const float dx = gcx - ac.x;
    const float dy = gcy - ac.y;
    mn1 = fminf(mn1, sqrtf(dx * dx + dy * dy));
  }
  for (int j = tid; j < 1600; j += 1024) {
    const float2 ac = centers[32000 + j];
    const float dx = gcx - ac.x;
    const float dy = gcy - ac.y;
    mn2 = fminf(mn2, sqrtf(dx * dx + dy * dy));
  }
#pragma unroll
  for (int s = 32; s >= 1; s >>= 1) {
    mn0 = fminf(mn0, __shfl_xor(mn0, s, 64));
    mn1 = fminf(mn1, __shfl_xor(mn1, s, 64));
    mn2 = fminf(mn2, __shfl_xor(mn2, s, 64));
  }
  if (lane == 0) {
    s_wmin[0][wid] = mn0;
    s_wmin[1][wid] = mn1;
    s_wmin[2][wid] = mn2;
  }
  __syncthreads();  // barrier A

  // ---- phase B: bounds + fused collection re-scan
  const float T0 = ninth_of_16(s_wmin[0]);
  const float T1 = ninth_of_16(s_wmin[1]);
  const float T2 = ninth_of_16(s_wmin[2]);

  for (int j = tid; j < 25600; j += 1024) {
    const float2 ac = centers[j];
    const float dx = gcx - ac.x;
    const float dy = gcy - ac.y;
    const float dist = sqrtf(dx * dx + dy * dy);
    if (dist <= T0) {
      const unsigned int p = atomicAdd(&s_cnt[0], 1u);
      if (p < CAP)
        buf[0][p] = ((unsigned long long)__float_as_uint(dist) << 32) |
                    (unsigned long long)(unsigned int)j;
    }
  }
  for (int j = tid; j < 6400; j += 1024) {
    const float2 ac = centers[25600 + j];
    const float dx = gcx - ac.x;
    const float dy = gcy - ac.y;
    const float dist = sqrtf(dx * dx + dy * dy);
    if (dist <= T1) {
      const unsigned int p = atomicAdd(&s_cnt[1], 1u);
      if (p < CAP)
        buf[1][p] = ((unsigned long long)__float_as_uint(dist) << 32) |
                    (unsigned long long)(unsigned int)(25600 + j);
    }
  }
  for (int j = tid; j < 1600; j += 1024) {
    const float2 ac = centers[32000 + j];
    const float dx = gcx - ac.x;
    const float dy = gcy - ac.y;
    const float dist = sqrtf(dx * dx + dy * dy);
    if (dist <= T2) {
      const unsigned int p = atomicAdd(&s_cnt[2], 1u);
      if (p < CAP)
        buf[2][p] = ((unsigned long long)__float_as_uint(dist) << 32) |
                    (unsigned long long)(unsigned int)(32000 + j);
    }
  }
  __syncthreads();  // barrier B

  // ---- phase C: fused rank-select (m ~ 15-40 per level, keys unique)
#pragma unroll
  for (int lev = 0; lev < 3; ++lev) {
    const int m = (int)min(s_cnt[lev], (unsigned int)CAP);
    for (int i = tid; i < m; i += 1024) {
      const unsigned long long k = buf[lev][i];
      int r = 0;
      for (int q = 0; q < m; ++q) r += (buf[lev][q] < k);
      if (r < 9) winners[lev * 9 + r] = k;
    }
  }
  __syncthreads();  // barrier C
  if (wid != 0) return;  // wave 0 finishes; no more barriers

  unsigned int mycand = 0;
  if (lane < 27) mycand = (unsigned int)(winners[lane] & 0xffffffffu);

  // candidate IoUs + inside-gt test (lanes 0..26)
  float ov = 0.0f;
  bool inside = false;
  if (lane < 27) {
    const float4 ab = anchors[mycand];
    ov = iou_f(gb, ab);
    const float2 ac = centers[mycand];
    const float m1 = fminf(fminf(ac.x - gb.x, ac.y - gb.y),
                           fminf(gb.z - ac.x, gb.w - ac.y));
    inside = m1 > EPSF;
  }
  // thr = mean + std(ddof=1) over the 27 gathered IoUs
  float s = (lane < 27) ? ov : 0.0f;
#pragma unroll
  for (int sft = 32; sft >= 1; sft >>= 1) s += __shfl_xor(s, sft, 64);
  const float mean = s / 27.0f;
  float dev = (lane < 27) ? (ov - mean) : 0.0f;
  float s2 = dev * dev;
#pragma unroll
  for (int sft = 32; sft >= 1; sft >>= 1) s2 += __shfl_xor(s2, sft, 64);
  const float thr = mean + sqrtf(s2 / 26.0f);

  if (lane < 27 && inside && ov > thr) {
    atomicAdd(&cnt[b * MM + (int)mycand], 1u);
    gidx[b * MM + (int)mycand] = (unsigned int)g;  // only read when cnt==1
  }
}

// B1+B2 fused: each block owns 64 rows of one batch. Threads 0..63 resolve
// the assignment (labels/bbox/fg) and stash (label,iou) in LDS; then all 320
// threads stream the 64x80 one-hot*iou score slab as coalesced float4.
__global__ __launch_bounds__(320) void k_out(
    const float4* __restrict__ anchors, const float4* __restrict__ gtb,
    const int* __restrict__ glabels, const float4* __restrict__ predb,
    const unsigned int* __restrict__ cnt, const unsigned int* __restrict__ gidx,
    float* __restrict__ out_labels, float4* __restrict__ out_bbox,
    float* __restrict__ out_fg, float4* __restrict__ out_scores) {
  const int t = threadIdx.x;
  const int b = blockIdx.y;
  const int row0 = blockIdx.x * 64;  // 525*64 == 33600 exact

  __shared__ int s_lbl[64];
  __shared__ float s_iou[64];

  if (t < 64) {
    const int a = row0 + t;
    const int i = b * MM + a;
    const unsigned int c = cnt[i];
    int g = 0;
    const bool fg = (c != 0u);
    if (c == 1u) {
      g = (int)gidx[i];
    } else if (c > 1u) {
      // reference: column replaced by one_hot(argmax_g overlaps) — includes
      // masked gts; first-max tie-break like jnp.argmax.
      const float4 ab = anchors[a];
      float best = -1.0f;
      for (int gg = 0; gg < NGT; ++gg) {
        const float ovv = iou_f(gtb[b * NGT + gg], ab);
        if (ovv > best) { best = ovv; g = gg; }
      }
    }
    const int lbl = fg ? glabels[b * NGT + g] : BGI;
    out_labels[i] = (float)lbl;
    out_bbox[i] = gtb[b * NGT + g];  // !fg -> g==0 (argmax of zeros)
    const float io = fg ? iou_f(gtb[b * NGT + g], predb[i]) : 0.0f;
    out_fg[i] = fg ? 1.0f : 0.0f;
    s_lbl[t] = fg ? lbl : -1;
    s_iou[t] = io;
  }
  __syncthreads();

  // 64 rows * 20 float4 = 1280 float4; 320 threads * 4 iters, coalesced.
  const size_t base = ((size_t)b * MM + row0) * 20;
#pragma unroll
  for (int it = 0; it < 4; ++it) {
    const int idx = it * 320 + t;
    const int row = idx / 20;          // magic-mul, compile-time const 20
    const int c4 = idx - row * 20;
    const int lbl = s_lbl[row];
    const float io = s_iou[row];
    const int cb = c4 * 4;
    float4 v;
    v.x = (lbl == cb) ? io : 0.0f;
    v.y = (lbl == cb + 1) ? io : 0.0f;
    v.z = (lbl == cb + 2) ? io : 0.0f;
    v.w = (lbl == cb + 3) ? io : 0.0f;
    out_scores[base + idx] = v;
  }
}

extern "C" void kernel_launch(void* const* d_in, const int* in_sizes, int n_in,
                              void* d_out, int out_size, void* d_ws, size_t ws_size,
                              hipStream_t stream) {
  // Identify inputs by size (robust to how the n_level tuple is passed).
  const float* anchors = nullptr;
  const float* gtb = nullptr;
  const int* glab = nullptr;
  const float* maskgt = nullptr;
  const float* predb = nullptr;
  int seen512 = 0;
  for (int i = 0; i < n_in; ++i) {
    const int sz = in_sizes[i];
    if (sz == 134400 && !anchors) anchors = (const float*)d_in[i];
    else if (sz == 2048 && !gtb) gtb = (const float*)d_in[i];
    else if (sz == 512) {
      if (seen512++ == 0) glab = (const int*)d_in[i];
      else maskgt = (const float*)d_in[i];
    } else if (sz == 2150400 && !predb) predb = (const float*)d_in[i];
  }
  if (!anchors || !gtb || !glab || !maskgt || !predb) return;  // defensive

  float* out = (float*)d_out;
  float* out_labels = out;                          // [B*M]
  float4* out_bbox = (float4*)(out + 537600);       // [B*M][4]
  float4* out_scores = (float4*)(out + 2688000);    // [B*M][80]
  float* out_fg = out + 45696000;                   // [B*M]

  unsigned int* cnt = (unsigned int*)d_ws;          // [B*M]
  unsigned int* gidx = cnt + 537600;                // [B*M]
  float2* centers = (float2*)(gidx + 537600);       // [M], 8B-aligned

  k_prep<<<dim3(2100), dim3(256), 0, stream>>>(
      (const float4*)anchors, centers, cnt);

  k_topk<<<dim3(BB * NGT), dim3(1024), 0, stream>>>(
      (const float4*)anchors, centers, (const float4*)gtb, maskgt, cnt, gidx);

  k_out<<<dim3(525, BB), dim3(320), 0, stream>>>(
      (const float4*)anchors, (const float4*)gtb, glab, (const float4*)predb,
      cnt, gidx, out_labels, out_bbox, out_fg, out_scores);
}

// Round 8
// 63.781 us; speedup vs baseline: 1.3481x; 1.3481x over previous
//
#include <hip/hip_runtime.h>
#include <stdint.h>

#define NCLS 80
#define BGI 80
#define BB 16
#define NGT 32
#define MM 33600
#define EPSF 1e-9f
#define CAP 1024

// IoU exactly mirroring reference pairwise_iou op order; no FMA contraction.
__device__ __forceinline__ float iou_f(const float4 b1, const float4 b2) {
#pragma clang fp contract(off)
  float ltx = fmaxf(b1.x, b2.x);
  float lty = fmaxf(b1.y, b2.y);
  float rbx = fminf(b1.z, b2.z);
  float rby = fminf(b1.w, b2.w);
  float iw = fmaxf(rbx - ltx, 0.0f);
  float ih = fmaxf(rby - lty, 0.0f);
  float inter = iw * ih;
  float a1 = (b1.z - b1.x) * (b1.w - b1.y);
  float a2 = (b2.z - b2.x) * (b2.w - b2.y);
  return inter / (a1 + a2 - inter + EPSF);
}

// P0: precompute anchor centers (same op order as reference anchor_points)
// and zero the packed (cnt|g-sum) scatter array. 2100*256 == 537600 exact.
__global__ __launch_bounds__(256) void k_prep(
    const float4* __restrict__ anchors, float2* __restrict__ centers,
    unsigned int* __restrict__ pk) {
#pragma clang fp contract(off)
  const int i = blockIdx.x * 256 + threadIdx.x;
  if (i < MM) {
    const float4 ab = anchors[i];
    centers[i] = make_float2((ab.x + ab.z) * 0.5f, (ab.y + ab.w) * 0.5f);
  }
  pk[i] = 0u;
}

// K1: one 1024-thread block per (b,g). Bound-then-rank top-9 per level:
//  pass1: per-thread min of SQUARED dist -> 16 wave minima; wave 0 computes
//         T = sqrt(9th smallest) (monotone sqrt commutes with min/rank, so
//         the bound equals the sqrt-domain one; valid upper bound on the
//         true 9th distance: <9 elements can be strictly below it).
//  pass2: dist = sqrt(d2) (same rounding as reference); collect keys
//         (distbits<<32|idx) with dist<=T into LDS.
//  rank:  key rank = #smaller keys; unique -> rank<9 are the exact top-9
//         with jax top_k tie semantics (equal dist -> smaller index).
// Structure (barriers, wave-0-only T) identical to the 70.3us-proven run.
__global__ __launch_bounds__(1024) void k_topk(
    const float4* __restrict__ anchors, const float2* __restrict__ centers,
    const float4* __restrict__ gtb, const float* __restrict__ maskgt,
    unsigned int* __restrict__ pk) {
#pragma clang fp contract(off)
  const int pair = blockIdx.x;            // b*32+g
  if (maskgt[pair] == 0.0f) return;       // masked gt contributes nothing
  const int b = pair >> 5;
  const int g = pair & 31;
  const int tid = threadIdx.x;
  const int lane = tid & 63;
  const int wid = tid >> 6;
  const float4 gb = gtb[pair];
  const float gcx = (gb.x + gb.z) * 0.5f;
  const float gcy = (gb.y + gb.w) * 0.5f;

  __shared__ unsigned long long buf[CAP];
  __shared__ unsigned long long winners[27];
  __shared__ float s_wmin[16];
  __shared__ float s_T;
  __shared__ unsigned int s_cnt;

  const int LSTART[3] = {0, 25600, 32000};
  const int LLEN[3]   = {25600, 6400, 1600};

#pragma unroll
  for (int lev = 0; lev < 3; ++lev) {
    const int start = LSTART[lev];
    const int len = LLEN[lev];

    // pass 1: branch-free per-thread min of squared distance (no sqrt)
    float mymin = 3.4e38f;
    for (int j = tid; j < len; j += 1024) {
      const float2 ac = centers[start + j];
      const float dx = gcx - ac.x;
      const float dy = gcy - ac.y;
      mymin = fminf(mymin, dx * dx + dy * dy);
    }
#pragma unroll
    for (int s = 32; s >= 1; s >>= 1)
      mymin = fminf(mymin, __shfl_xor(mymin, s, 64));
    if (lane == 0) s_wmin[wid] = mymin;
    if (tid == 0) s_cnt = 0u;
    __syncthreads();

    // T = sqrt(9th smallest of the 16 squared wave minima), wave 0 only
    if (wid == 0 && lane < 16) {
      const float v = s_wmin[lane];
      int r = 0;
#pragma unroll
      for (int q = 0; q < 16; ++q) {
        const float o = s_wmin[q];
        r += (o < v) || (o == v && q < lane);
      }
      if (r == 8) s_T = sqrtf(v);  // unique rank -> exactly one lane
    }
    __syncthreads();
    const float T = s_T;

    // pass 2: collect candidates with sqrt'd dist (reference rounding)
    for (int j = tid; j < len; j += 1024) {
      const float2 ac = centers[start + j];
      const float dx = gcx - ac.x;
      const float dy = gcy - ac.y;
      const float dist = sqrtf(dx * dx + dy * dy);
      if (dist <= T) {
        const unsigned int p = atomicAdd(&s_cnt, 1u);
        if (p < CAP)
          buf[p] = ((unsigned long long)__float_as_uint(dist) << 32) |
                   (unsigned long long)(unsigned int)(start + j);
      }
    }
    __syncthreads();
    const int m = (int)min(s_cnt, (unsigned int)CAP);

    // rank-select: exactly 9 winners (keys unique -> ranks unique)
    for (int i = tid; i < m; i += 1024) {
      const unsigned long long k = buf[i];
      int r = 0;
      for (int q = 0; q < m; ++q) r += (buf[q] < k);
      if (r < 9) winners[lev * 9 + r] = k;
    }
    __syncthreads();
  }

  if (wid != 0) return;  // wave 0 finishes; no more barriers

  unsigned int mycand = 0;
  if (lane < 27) mycand = (unsigned int)(winners[lane] & 0xffffffffu);

  // candidate IoUs + inside-gt test (lanes 0..26)
  float ov = 0.0f;
  bool inside = false;
  if (lane < 27) {
    const float4 ab = anchors[mycand];
    ov = iou_f(gb, ab);
    const float2 ac = centers[mycand];
    const float m1 = fminf(fminf(ac.x - gb.x, ac.y - gb.y),
                           fminf(gb.z - ac.x, gb.w - ac.y));
    inside = m1 > EPSF;
  }
  // thr = mean + std(ddof=1) over the 27 gathered IoUs
  float s = (lane < 27) ? ov : 0.0f;
#pragma unroll
  for (int sft = 32; sft >= 1; sft >>= 1) s += __shfl_xor(s, sft, 64);
  const float mean = s / 27.0f;
  float dev = (lane < 27) ? (ov - mean) : 0.0f;
  float s2 = dev * dev;
#pragma unroll
  for (int sft = 32; sft >= 1; sft >>= 1) s2 += __shfl_xor(s2, sft, 64);
  const float thr = mean + sqrtf(s2 / 26.0f);

  if (lane < 27 && inside && ov > thr) {
    // packed: cnt in bits[31:20], sum of g in bits[19:0].
    // <=32 adds: cnt<=32, g-sum<=992 -> no field overflow; cnt==1 -> low=g.
    atomicAdd(&pk[b * MM + (int)mycand], (1u << 20) | (unsigned int)g);
  }
}

// B1+B2 fused: each block owns 64 rows of one batch. Threads 0..63 resolve
// the assignment (labels/bbox/fg) and stash (label,iou) in LDS; then all 320
// threads stream the 64x80 one-hot*iou score slab as coalesced float4.
__global__ __launch_bounds__(320) void k_out(
    const float4* __restrict__ anchors, const float4* __restrict__ gtb,
    const int* __restrict__ glabels, const float4* __restrict__ predb,
    const unsigned int* __restrict__ pk,
    float* __restrict__ out_labels, float4* __restrict__ out_bbox,
    float* __restrict__ out_fg, float4* __restrict__ out_scores) {
  const int t = threadIdx.x;
  const int b = blockIdx.y;
  const int row0 = blockIdx.x * 64;  // 525*64 == 33600 exact

  __shared__ int s_lbl[64];
  __shared__ float s_iou[64];

  if (t < 64) {
    const int a = row0 + t;
    const int i = b * MM + a;
    const unsigned int p = pk[i];
    const unsigned int c = p >> 20;
    int g = 0;
    const bool fg = (c != 0u);
    if (c == 1u) {
      g = (int)(p & 0xFFFFFu);
    } else if (c > 1u) {
      // reference: column replaced by one_hot(argmax_g overlaps) — includes
      // masked gts; first-max tie-break like jnp.argmax.
      const float4 ab = anchors[a];
      float best = -1.0f;
      for (int gg = 0; gg < NGT; ++gg) {
        const float ovv = iou_f(gtb[b * NGT + gg], ab);
        if (ovv > best) { best = ovv; g = gg; }
      }
    }
    const int lbl = fg ? glabels[b * NGT + g] : BGI;
    out_labels[i] = (float)lbl;
    out_bbox[i] = gtb[b * NGT + g];  // !fg -> g==0 (argmax of zeros)
    const float io = fg ? iou_f(gtb[b * NGT + g], predb[i]) : 0.0f;
    out_fg[i] = fg ? 1.0f : 0.0f;
    s_lbl[t] = fg ? lbl : -1;
    s_iou[t] = io;
  }
  __syncthreads();

  // 64 rows * 20 float4 = 1280 float4; 320 threads * 4 iters, coalesced.
  const size_t base = ((size_t)b * MM + row0) * 20;
#pragma unroll
  for (int it = 0; it < 4; ++it) {
    const int idx = it * 320 + t;
    const int row = idx / 20;          // magic-mul, compile-time const 20
    const int c4 = idx - row * 20;
    const int lbl = s_lbl[row];
    const float io = s_iou[row];
    const int cb = c4 * 4;
    float4 v;
    v.x = (lbl == cb) ? io : 0.0f;
    v.y = (lbl == cb + 1) ? io : 0.0f;
    v.z = (lbl == cb + 2) ? io : 0.0f;
    v.w = (lbl == cb + 3) ? io : 0.0f;
    out_scores[base + idx] = v;
  }
}

extern "C" void kernel_launch(void* const* d_in, const int* in_sizes, int n_in,
                              void* d_out, int out_size, void* d_ws, size_t ws_size,
                              hipStream_t stream) {
  // Identify inputs by size (robust to how the n_level tuple is passed).
  const float* anchors = nullptr;
  const float* gtb = nullptr;
  const int* glab = nullptr;
  const float* maskgt = nullptr;
  const float* predb = nullptr;
  int seen512 = 0;
  for (int i = 0; i < n_in; ++i) {
    const int sz = in_sizes[i];
    if (sz == 134400 && !anchors) anchors = (const float*)d_in[i];
    else if (sz == 2048 && !gtb) gtb = (const float*)d_in[i];
    else if (sz == 512) {
      if (seen512++ == 0) glab = (const int*)d_in[i];
      else maskgt = (const float*)d_in[i];
    } else if (sz == 2150400 && !predb) predb = (const float*)d_in[i];
  }
  if (!anchors || !gtb || !glab || !maskgt || !predb) return;  // defensive

  float* out = (float*)d_out;
  float* out_labels = out;                          // [B*M]
  float4* out_bbox = (float4*)(out + 537600);       // [B*M][4]
  float4* out_scores = (float4*)(out + 2688000);    // [B*M][80]
  float* out_fg = out + 45696000;                   // [B*M]

  unsigned int* pk = (unsigned int*)d_ws;           // [B*M] packed cnt|gsum
  float2* centers = (float2*)(pk + 537600);         // [M], 8B-aligned

  k_prep<<<dim3(2100), dim3(256), 0, stream>>>(
      (const float4*)anchors, centers, pk);

  k_topk<<<dim3(BB * NGT), dim3(1024), 0, stream>>>(
      (const float4*)anchors, centers, (const float4*)gtb, maskgt, pk);

  k_out<<<dim3(525, BB), dim3(320), 0, stream>>>(
      (const float4*)anchors, (const float4*)gtb, glab, (const float4*)predb,
      pk, out_labels, out_bbox, out_fg, out_scores);
}

// Round 9
// 59.382 us; speedup vs baseline: 1.4480x; 1.0741x over previous
//
#include <hip/hip_runtime.h>
#include <stdint.h>

#define NCLS 80
#define BGI 80
#define BB 16
#define NGT 32
#define MM 33600
#define EPSF 1e-9f
#define CAP 1024
#define ZPB 21000  // float4 zero-slice per k_topk block (512*21000 == 10752000)

// IoU exactly mirroring reference pairwise_iou op order; no FMA contraction.
__device__ __forceinline__ float iou_f(const float4 b1, const float4 b2) {
#pragma clang fp contract(off)
  float ltx = fmaxf(b1.x, b2.x);
  float lty = fmaxf(b1.y, b2.y);
  float rbx = fminf(b1.z, b2.z);
  float rby = fminf(b1.w, b2.w);
  float iw = fmaxf(rbx - ltx, 0.0f);
  float ih = fmaxf(rby - lty, 0.0f);
  float inter = iw * ih;
  float a1 = (b1.z - b1.x) * (b1.w - b1.y);
  float a2 = (b2.z - b2.x) * (b2.w - b2.y);
  return inter / (a1 + a2 - inter + EPSF);
}

// P0: precompute anchor centers (same op order as reference anchor_points)
// and zero the packed (cnt|g-sum) scatter array. 2100*256 == 537600 exact.
__global__ __launch_bounds__(256) void k_prep(
    const float4* __restrict__ anchors, float2* __restrict__ centers,
    unsigned int* __restrict__ pk) {
#pragma clang fp contract(off)
  const int i = blockIdx.x * 256 + threadIdx.x;
  if (i < MM) {
    const float4 ab = anchors[i];
    centers[i] = make_float2((ab.x + ab.z) * 0.5f, (ab.y + ab.w) * 0.5f);
  }
  pk[i] = 0u;
}

// Fire-and-forget zeroing of 1/3 of this block's score slice. No one reads
// these in-kernel; drain overlaps the latency-bound scan phases.
__device__ __forceinline__ void zstores(float4* __restrict__ zs,
                                        const int base, const int site,
                                        const int tid) {
#pragma unroll
  for (int it = 0; it < 7; ++it) {
    const int idx = site * 7168 + it * 1024 + tid;
    if (idx < ZPB) zs[base + idx] = make_float4(0.f, 0.f, 0.f, 0.f);
  }
}

// K1: one 1024-thread block per (b,g). Bound-then-rank top-9 per level
// (structure identical to the 63.8us-proven run) + interleaved score-zeroing.
//  pass1: per-thread min of SQUARED dist -> 16 wave minima; wave 0 computes
//         T = sqrt(9th smallest) (monotone sqrt commutes with min/rank).
//         T is a valid upper bound: <9 elements can be strictly below K9.
//  pass2: dist = sqrt(d2) (reference rounding); collect keys
//         (distbits<<32|idx) with dist<=T into LDS.
//  rank:  key rank = #smaller keys; unique -> rank<9 are the exact top-9
//         with jax top_k tie semantics (equal dist -> smaller index).
__global__ __launch_bounds__(1024) void k_topk(
    const float4* __restrict__ anchors, const float2* __restrict__ centers,
    const float4* __restrict__ gtb, const float* __restrict__ maskgt,
    unsigned int* __restrict__ pk, float4* __restrict__ zscores) {
#pragma clang fp contract(off)
  const int pair = blockIdx.x;            // b*32+g
  const int tid = threadIdx.x;
  const int zbase = pair * ZPB;

  zstores(zscores, zbase, 0, tid);        // site 0: overlaps pass-1 scan

  if (maskgt[pair] == 0.0f) {             // masked gt: just finish zeroing
    zstores(zscores, zbase, 1, tid);
    zstores(zscores, zbase, 2, tid);
    return;
  }
  const int b = pair >> 5;
  const int g = pair & 31;
  const int lane = tid & 63;
  const int wid = tid >> 6;
  const float4 gb = gtb[pair];
  const float gcx = (gb.x + gb.z) * 0.5f;
  const float gcy = (gb.y + gb.w) * 0.5f;

  __shared__ unsigned long long buf[CAP];
  __shared__ unsigned long long winners[27];
  __shared__ float s_wmin[16];
  __shared__ float s_T;
  __shared__ unsigned int s_cnt;

  const int LSTART[3] = {0, 25600, 32000};
  const int LLEN[3]   = {25600, 6400, 1600};

#pragma unroll
  for (int lev = 0; lev < 3; ++lev) {
    const int start = LSTART[lev];
    const int len = LLEN[lev];

    // pass 1: branch-free per-thread min of squared distance (no sqrt)
    float mymin = 3.4e38f;
    for (int j = tid; j < len; j += 1024) {
      const float2 ac = centers[start + j];
      const float dx = gcx - ac.x;
      const float dy = gcy - ac.y;
      mymin = fminf(mymin, dx * dx + dy * dy);
    }
#pragma unroll
    for (int s = 32; s >= 1; s >>= 1)
      mymin = fminf(mymin, __shfl_xor(mymin, s, 64));
    if (lane == 0) s_wmin[wid] = mymin;
    if (tid == 0) s_cnt = 0u;
    __syncthreads();

    if (lev == 0) zstores(zscores, zbase, 1, tid);  // drains under pass 2

    // T = sqrt(9th smallest of the 16 squared wave minima), wave 0 only
    if (wid == 0 && lane < 16) {
      const float v = s_wmin[lane];
      int r = 0;
#pragma unroll
      for (int q = 0; q < 16; ++q) {
        const float o = s_wmin[q];
        r += (o < v) || (o == v && q < lane);
      }
      if (r == 8) s_T = sqrtf(v);  // unique rank -> exactly one lane
    }
    __syncthreads();
    const float T = s_T;

    // pass 2: collect candidates with sqrt'd dist (reference rounding)
    for (int j = tid; j < len; j += 1024) {
      const float2 ac = centers[start + j];
      const float dx = gcx - ac.x;
      const float dy = gcy - ac.y;
      const float dist = sqrtf(dx * dx + dy * dy);
      if (dist <= T) {
        const unsigned int p = atomicAdd(&s_cnt, 1u);
        if (p < CAP)
          buf[p] = ((unsigned long long)__float_as_uint(dist) << 32) |
                   (unsigned long long)(unsigned int)(start + j);
      }
    }
    __syncthreads();

    if (lev == 0) zstores(zscores, zbase, 2, tid);  // drains under rank+L1/L2

    const int m = (int)min(s_cnt, (unsigned int)CAP);
    // rank-select: exactly 9 winners (keys unique -> ranks unique)
    for (int i = tid; i < m; i += 1024) {
      const unsigned long long k = buf[i];
      int r = 0;
      for (int q = 0; q < m; ++q) r += (buf[q] < k);
      if (r < 9) winners[lev * 9 + r] = k;
    }
    __syncthreads();
  }

  if (wid != 0) return;  // wave 0 finishes; no more barriers

  unsigned int mycand = 0;
  if (lane < 27) mycand = (unsigned int)(winners[lane] & 0xffffffffu);

  // candidate IoUs + inside-gt test (lanes 0..26)
  float ov = 0.0f;
  bool inside = false;
  if (lane < 27) {
    const float4 ab = anchors[mycand];
    ov = iou_f(gb, ab);
    const float2 ac = centers[mycand];
    const float m1 = fminf(fminf(ac.x - gb.x, ac.y - gb.y),
                           fminf(gb.z - ac.x, gb.w - ac.y));
    inside = m1 > EPSF;
  }
  // thr = mean + std(ddof=1) over the 27 gathered IoUs
  float s = (lane < 27) ? ov : 0.0f;
#pragma unroll
  for (int sft = 32; sft >= 1; sft >>= 1) s += __shfl_xor(s, sft, 64);
  const float mean = s / 27.0f;
  float dev = (lane < 27) ? (ov - mean) : 0.0f;
  float s2 = dev * dev;
#pragma unroll
  for (int sft = 32; sft >= 1; sft >>= 1) s2 += __shfl_xor(s2, sft, 64);
  const float thr = mean + sqrtf(s2 / 26.0f);

  if (lane < 27 && inside && ov > thr) {
    // packed: cnt in bits[31:20], sum of g in bits[19:0].
    // <=32 adds: cnt<=32, g-sum<=992 -> no field overflow; cnt==1 -> low=g.
    atomicAdd(&pk[b * MM + (int)mycand], (1u << 20) | (unsigned int)g);
  }
}

// B1 sparse: per (b,a) resolve assignment; write labels/bbox/fg and — since
// the score tensor is pre-zeroed by k_topk — ONE scalar score per fg anchor.
__global__ __launch_bounds__(256) void k_out(
    const float4* __restrict__ anchors, const float4* __restrict__ gtb,
    const int* __restrict__ glabels, const float4* __restrict__ predb,
    const unsigned int* __restrict__ pk,
    float* __restrict__ out_labels, float4* __restrict__ out_bbox,
    float* __restrict__ out_fg, float* __restrict__ out_scores) {
  const int a = blockIdx.x * 256 + threadIdx.x;
  if (a >= MM) return;
  const int b = blockIdx.y;
  const int i = b * MM + a;
  const unsigned int p = pk[i];
  const unsigned int c = p >> 20;
  int g = 0;
  const bool fg = (c != 0u);
  if (c == 1u) {
    g = (int)(p & 0xFFFFFu);
  } else if (c > 1u) {
    // reference: column replaced by one_hot(argmax_g overlaps) — includes
    // masked gts; first-max tie-break like jnp.argmax.
    const float4 ab = anchors[a];
    float best = -1.0f;
    for (int gg = 0; gg < NGT; ++gg) {
      const float ovv = iou_f(gtb[b * NGT + gg], ab);
      if (ovv > best) { best = ovv; g = gg; }
    }
  }
  const int lbl = fg ? glabels[b * NGT + g] : BGI;
  out_labels[i] = (float)lbl;
  out_bbox[i] = gtb[b * NGT + g];  // !fg -> g==0 (argmax of zeros)
  out_fg[i] = fg ? 1.0f : 0.0f;
  if (fg) {
    const float io = iou_f(gtb[b * NGT + g], predb[i]);
    out_scores[(size_t)i * NCLS + lbl] = io;  // rest of row stays zero
  }
}

extern "C" void kernel_launch(void* const* d_in, const int* in_sizes, int n_in,
                              void* d_out, int out_size, void* d_ws, size_t ws_size,
                              hipStream_t stream) {
  // Identify inputs by size (robust to how the n_level tuple is passed).
  const float* anchors = nullptr;
  const float* gtb = nullptr;
  const int* glab = nullptr;
  const float* maskgt = nullptr;
  const float* predb = nullptr;
  int seen512 = 0;
  for (int i = 0; i < n_in; ++i) {
    const int sz = in_sizes[i];
    if (sz == 134400 && !anchors) anchors = (const float*)d_in[i];
    else if (sz == 2048 && !gtb) gtb = (const float*)d_in[i];
    else if (sz == 512) {
      if (seen512++ == 0) glab = (const int*)d_in[i];
      else maskgt = (const float*)d_in[i];
    } else if (sz == 2150400 && !predb) predb = (const float*)d_in[i];
  }
  if (!anchors || !gtb || !glab || !maskgt || !predb) return;  // defensive

  float* out = (float*)d_out;
  float* out_labels = out;                          // [B*M]
  float4* out_bbox = (float4*)(out + 537600);       // [B*M][4]
  float* out_scores = out + 2688000;                // [B*M][80]
  float* out_fg = out + 45696000;                   // [B*M]

  unsigned int* pk = (unsigned int*)d_ws;           // [B*M] packed cnt|gsum
  float2* centers = (float2*)(pk + 537600);         // [M], 8B-aligned

  k_prep<<<dim3(2100), dim3(256), 0, stream>>>(
      (const float4*)anchors, centers, pk);

  k_topk<<<dim3(BB * NGT), dim3(1024), 0, stream>>>(
      (const float4*)anchors, centers, (const float4*)gtb, maskgt, pk,
      (float4*)out_scores);

  k_out<<<dim3(132, BB), dim3(256), 0, stream>>>(
      (const float4*)anchors, (const float4*)gtb, glab, (const float4*)predb,
      pk, out_labels, out_bbox, out_fg, out_scores);
}